// Round 2
// baseline (340.802 us; speedup 1.0000x reference)
//
#include <hip/hip_runtime.h>
#include <cfloat>
#include <math.h>

#define NPTS   5000
#define BATCH  2
#define DIM    128
#define NBINS  10
#define BINSZ  500
#define TOPK   5
#define ROTCOLS 100   // rotations stored [128, 100]; we use first NBINS/2 = 5

// ---------------- Kernel A: bin assignment + squared norms (fp64 acc) -----
#define KB_PTS 64
#define KB_STR 129
__global__ void k_bins(const float* __restrict__ pts, const float* __restrict__ rot,
                       int* __restrict__ bin_idx, double* __restrict__ na) {
    __shared__ float P[KB_PTS * KB_STR];
    __shared__ float rotL[DIM * 5];
    int tid = threadIdx.x;
    for (int f = tid; f < DIM * 5; f += 256)
        rotL[f] = rot[(f / 5) * ROTCOLS + (f % 5)];

    int p0  = blockIdx.x * KB_PTS;
    int npb = min(KB_PTS, BATCH * NPTS - p0);

    for (int f = tid; f < npb * DIM; f += 256) {
        int r = f >> 7, d = f & 127;
        P[r * KB_STR + d] = pts[(size_t)(p0 + r) * DIM + d];
    }
    __syncthreads();

    int p = tid >> 2;    // point within block
    int s = tid & 3;     // dim quarter
    double acc[5] = {0., 0., 0., 0., 0.};
    double sq = 0.;
    const float* row = &P[p * KB_STR + s * 32];
    for (int j = 0; j < 32; ++j) {
        double v = (double)row[j];
        sq += v * v;
        int d = s * 32 + j;
#pragma unroll
        for (int h = 0; h < 5; ++h) acc[h] += v * (double)rotL[d * 5 + h];
    }
#pragma unroll
    for (int m = 1; m < 4; m <<= 1) {
#pragma unroll
        for (int h = 0; h < 5; ++h) acc[h] += __shfl_xor(acc[h], m, 4);
        sq += __shfl_xor(sq, m, 4);
    }
    if (s == 0 && p < npb) {
        double best = acc[0]; int bc = 0;
#pragma unroll
        for (int c = 1; c < NBINS; ++c) {
            double v = (c < 5) ? acc[c] : -acc[c - 5];
            if (v > best) { best = v; bc = c; }
        }
        bin_idx[p0 + p] = bc;
        na[p0 + p] = sq;
    }
}

// ---------------- Kernel B: stable counting sort (== stable argsort) ------
__global__ void k_sort(const int* __restrict__ bin_idx, int* __restrict__ order) {
    const int b = blockIdx.x;
    const int t = threadIdx.x;               // 256 threads
    const int NPT = (NPTS + 255) / 256;      // 20
    int start = t * NPT;
    int end   = min(NPTS, start + NPT);

    int cnt[NBINS];
#pragma unroll
    for (int c = 0; c < NBINS; ++c) cnt[c] = 0;
    for (int i = start; i < end; ++i) {
        int c = bin_idx[b * NPTS + i];
#pragma unroll
        for (int k = 0; k < NBINS; ++k) cnt[k] += (c == k);
    }

    __shared__ int hist[NBINS * 256];
#pragma unroll
    for (int c = 0; c < NBINS; ++c) hist[c * 256 + t] = cnt[c];
    __syncthreads();

    int base = t * NBINS;
    int s = 0;
#pragma unroll
    for (int k = 0; k < NBINS; ++k) s += hist[base + k];
    __shared__ int scan[256];
    scan[t] = s;
    __syncthreads();
    for (int off = 1; off < 256; off <<= 1) {
        int v = (t >= off) ? scan[t - off] : 0;
        __syncthreads();
        scan[t] += v;
        __syncthreads();
    }
    int run = scan[t] - s;
#pragma unroll
    for (int k = 0; k < NBINS; ++k) { int h = hist[base + k]; hist[base + k] = run; run += h; }
    __syncthreads();

    int ofs[NBINS];
#pragma unroll
    for (int c = 0; c < NBINS; ++c) ofs[c] = hist[c * 256 + t];
    for (int i = start; i < end; ++i) {
        int c = bin_idx[b * NPTS + i];
        int pos = 0;
#pragma unroll
        for (int k = 0; k < NBINS; ++k) {
            if (c == k) pos = ofs[k];
            ofs[k] += (c == k);
        }
        order[b * NPTS + pos] = i;
    }
}

// -- Kernel C: probed f64 MFMA gram + top-5 + zero-fill/scatter ------------
// R0's MFMA attempt (assumed A: i=lane&15,k=lane>>4; B: j=lane&15,k=lane>>4;
// D: row=4*(lane>>4)+reg, col=lane&15) failed absmax~1.0 -> fragment layout
// for f64 16x16x4 is UNVERIFIED on gfx950 (m89's dtype-independence claim
// covers bf16/f16/fp8/fp6/fp4/i8 only). This version PROBES the A and B
// conventions at runtime with two 1-MFMA identities:
//   probe B: A==1 (convention-invariant), B=lane -> D[.][j] = 4j+96 (conv1:
//            j=lane&15,k=lane>>4) vs 16j+6 (conv2: j=lane>>2,k=lane&3)
//   probe A: B==1, A=lane -> rowsum 4i+96 (conv1) vs 16i+6 (conv2); pattern
//            also validates the assumed D row/reg interleave.
// If neither matches (exotic layout / broken f64 MFMA), fall back to a
// scalar-f64 path computing the SAME (4 rows x 1 col)/lane ownership, so the
// kernel is correct in every case. Selection/merge/scatter identical to R0.
#define RT    16
#define NRT   32
#define CTILE 64
#define RSTRD 130      // rowPd stride in doubles (1040 B rows, 16B-aligned)
#define CSTR  132      // colP stride in floats
#define NCT   8
#define ROWQ  (NPTS/4)

typedef double v4d __attribute__((ext_vector_type(4)));

__launch_bounds__(256, 3)
__global__ void k_chunks(const float* __restrict__ pts, const double* __restrict__ na,
                         const int* __restrict__ order, float* __restrict__ out) {
    __shared__ double rowPd[RT * RSTRD];    // 16640 B (reused as merge buffer at end)
    __shared__ float  colP[CTILE * CSTR];   // 33792 B
    __shared__ double naC[CTILE];
    __shared__ double naRs[RT];
    __shared__ int    ordR[RT];             // ~51.1 KB -> 3 blocks/CU

    int blk   = blockIdx.x;
    int rt    = blk & (NRT - 1);
    int chunk = blk >> 5;          // 0..19
    int b     = chunk / NBINS;
    int c     = chunk % NBINS;
    int tid   = threadIdx.x;
    int row0  = rt * RT;
    int rowCount = min(RT, BINSZ - row0);   // 16, except last tile: 4

    const int*   ordBase = order + b * NPTS + c * BINSZ;
    const float* ptsB    = pts + (size_t)b * NPTS * DIM;

    int lane = tid & 63;
    int w    = tid >> 6;     // wave id 0..3 -> col slab [16w, 16w+16) per tile
    int mm   = lane & 15;
    int gg   = lane >> 4;

    // ---- layout probes (register-only; once per thread) ----
    v4d pz = {0., 0., 0., 0.};
    v4d pB = __builtin_amdgcn_mfma_f64_16x16x4f64(1.0, (double)lane, pz, 0, 0, 0);
    v4d pA = __builtin_amdgcn_mfma_f64_16x16x4f64((double)lane, 1.0, pz, 0, 0, 0);
    bool okB1 = true, okB2 = true, okA1 = true, okA2 = true;
#pragma unroll
    for (int r = 0; r < 4; ++r) {
        okB1 = okB1 && (pB[r] == (double)(4 * mm + 96));
        okB2 = okB2 && (pB[r] == (double)(16 * mm + 6));
        int rowr = 4 * gg + r;                 // trusted D interleave (validated by pattern)
        okA1 = okA1 && (pA[r] == (double)(4 * rowr + 96));
        okA2 = okA2 && (pA[r] == (double)(16 * rowr + 6));
    }
    int aconv = __all(okA1) ? 1 : (__all(okA2) ? 2 : 0);
    int bconv = __all(okB1) ? 1 : (__all(okB2) ? 2 : 0);
    bool useMfma = (aconv != 0) && (bconv != 0);
    int iA = (aconv == 2) ? (lane >> 2) : mm;
    int kA = (aconv == 2) ? (lane & 3)  : gg;
    int jB = (bconv == 2) ? (lane >> 2) : mm;
    int kB = (bconv == 2) ? (lane & 3)  : gg;

    // stage row points as doubles (gathered via order; cvt once per element)
    for (int f = tid; f < rowCount * (DIM / 4); f += 256) {
        int r = f >> 5;
        int q = f & 31;
        int g = ordBase[row0 + r];
        float4 v = *(const float4*)(ptsB + (size_t)g * DIM + q * 4);
        double2 d01; d01.x = (double)v.x; d01.y = (double)v.y;
        double2 d23; d23.x = (double)v.z; d23.y = (double)v.w;
        *(double2*)(&rowPd[r * RSTRD + q * 4 + 0]) = d01;
        *(double2*)(&rowPd[r * RSTRD + q * 4 + 2]) = d23;
    }
    if (tid < rowCount) {
        int g = ordBase[row0 + tid];
        ordR[tid] = g;
        naRs[tid] = na[b * NPTS + g];
    }
    __syncthreads();

    // per-lane rows (constant across tiles); rows >= rowCount discarded later
    double naR[4];
#pragma unroll
    for (int i = 0; i < 4; ++i) {
        int r = 4 * gg + i;
        naR[i] = (r < rowCount) ? naRs[r] : 0.;
    }

    // selection key: clamped squared distance (smaller = better); bottom-5,
    // strict < with in-order arrival == (key asc, idx asc) within a lane.
    double tv[4][TOPK];
    int    tl[4][TOPK];
#pragma unroll
    for (int i = 0; i < 4; ++i)
#pragma unroll
        for (int k = 0; k < TOPK; ++k) { tv[i][k] = DBL_MAX; tl[i][k] = 0x7fffffff; }

    const int totalZ = rowCount * ROWQ;

    const double* aBase = &rowPd[iA * RSTRD + kA];          // A[iA][4s+kA]
    const float*  bBase = &colP[(16 * w + jB) * CSTR + kB]; // B col 16w+jB, dim 4s+kB

    for (int ct = 0; ct < NCT; ++ct) {
        int col0 = ct * CTILE;
        int colCount = min(CTILE, BINSZ - col0);
        __syncthreads();   // prev tile's readers done before restage
        for (int f = tid; f < colCount * (DIM / 4); f += 256) {
            int j = f >> 5;
            int q = f & 31;
            int g = ordBase[col0 + j];
            float4 v = *(const float4*)(ptsB + (size_t)g * DIM + q * 4);
            *(float4*)(&colP[j * CSTR + q * 4]) = v;
        }
        if (tid < colCount) {
            int g = ordBase[col0 + tid];
            naC[tid] = na[b * NPTS + g];
        }
        __syncthreads();

        // zero-fill slice ct: stores drain during this tile's gram compute
        {
            float4 z = make_float4(0.f, 0.f, 0.f, 0.f);
            int z0 = (ct * totalZ) / NCT, z1 = ((ct + 1) * totalZ) / NCT;
            for (int f = z0 + tid; f < z1; f += 256) {
                int r = f / ROWQ;
                int q = f - r * ROWQ;
                float* outRow = out + ((size_t)b * NPTS + ordR[r]) * NPTS;
                *(float4*)(outRow + 4 * q) = z;
            }
        }

        // gram: this wave computes rows 0..15 x cols [16w,16w+16)
        v4d accv = {0., 0., 0., 0.};
        if (useMfma) {
#pragma unroll
            for (int s = 0; s < 32; ++s) {
                double av = aBase[4 * s];
                double bv = (double)bBase[4 * s];
                accv = __builtin_amdgcn_mfma_f64_16x16x4f64(av, bv, accv, 0, 0, 0);
            }
        } else {
            // scalar fallback, same ownership: rows 4gg+i, col 16w+mm
            const float*  bcol = &colP[(16 * w + mm) * CSTR];
            const double* r0 = &rowPd[(4 * gg + 0) * RSTRD];
            const double* r1 = &rowPd[(4 * gg + 1) * RSTRD];
            const double* r2 = &rowPd[(4 * gg + 2) * RSTRD];
            const double* r3 = &rowPd[(4 * gg + 3) * RSTRD];
            double s0 = 0., s1 = 0., s2 = 0., s3 = 0.;
#pragma unroll 4
            for (int q = 0; q < DIM; q += 4) {
                float4 bf = *(const float4*)(&bcol[q]);
                double b0 = (double)bf.x, b1 = (double)bf.y,
                       b2 = (double)bf.z, b3 = (double)bf.w;
                s0 += r0[q] * b0 + r0[q + 1] * b1 + r0[q + 2] * b2 + r0[q + 3] * b3;
                s1 += r1[q] * b0 + r1[q + 1] * b1 + r1[q + 2] * b2 + r1[q + 3] * b3;
                s2 += r2[q] * b0 + r2[q + 1] * b1 + r2[q + 2] * b2 + r2[q + 3] * b3;
                s3 += r3[q] * b0 + r3[q + 1] * b1 + r3[q + 2] * b2 + r3[q + 3] * b3;
            }
            accv[0] = s0; accv[1] = s1; accv[2] = s2; accv[3] = s3;
        }

        // running bottom-5: lane holds 4 rows x 1 col per tile; cols strictly
        // increasing across tiles -> strict < keeps earlier idx.
        {
            int j = 16 * w + mm;
            if (j < colCount) {
                int    cl = col0 + j;
                double nc = naC[j];
#pragma unroll
                for (int i = 0; i < 4; ++i) {
                    double cv = fmax(naR[i] + nc - 2. * accv[i], 1e-6);
                    int ci = cl;
#pragma unroll
                    for (int k = 0; k < TOPK; ++k) {
                        bool lt = (cv < tv[i][k]);
                        double ov = tv[i][k]; int ol = tl[i][k];
                        if (lt) { tv[i][k] = cv; tl[i][k] = ci; cv = ov; ci = ol; }
                    }
                }
            }
        }
    }

    // merge across the 16 lanes of each k-group (butterfly, width 16):
    // lanes 16*gg..16*gg+15 all hold lists for rows 4*gg..4*gg+3.
#pragma unroll
    for (int m = 1; m < 16; m <<= 1) {
#pragma unroll
        for (int i = 0; i < 4; ++i) {
            double rv[TOPK]; int rl[TOPK];
#pragma unroll
            for (int k = 0; k < TOPK; ++k) {
                rv[k] = __shfl_xor(tv[i][k], m, 16);
                rl[k] = __shfl_xor(tl[i][k], m, 16);
            }
#pragma unroll
            for (int k = 0; k < TOPK; ++k) {
                double cv = rv[k]; int cl = rl[k];
#pragma unroll
                for (int s = 0; s < TOPK; ++s) {   // (key asc, idx asc) total order
                    bool better = (cv < tv[i][s]) || (cv == tv[i][s] && cl < tl[i][s]);
                    double ov = tv[i][s]; int ol = tl[i][s];
                    if (better) { tv[i][s] = cv; tl[i][s] = cl; cv = ov; cl = ol; }
                }
            }
        }
    }

    // cross-wave merge: each wave saw only its 16-col slab per tile.
    // Reuse rowPd as the merge buffer (all gram reads are done).
    __syncthreads();   // gram reads done + drain zero slices
    double* mV = rowPd;                               // 4*16*5 = 320 doubles
    int*    mI = reinterpret_cast<int*>(rowPd + 320); // 320 ints
    if (mm == 0) {
#pragma unroll
        for (int i = 0; i < 4; ++i) {
            int r = 4 * gg + i;
#pragma unroll
            for (int k = 0; k < TOPK; ++k) {
                mV[(w * RT + r) * TOPK + k] = tv[i][k];
                mI[(w * RT + r) * TOPK + k] = tl[i][k];
            }
        }
    }
    __syncthreads();

    if (tid < RT && tid < rowCount) {
        int r = tid;
        double fv[TOPK]; int fl[TOPK];
#pragma unroll
        for (int k = 0; k < TOPK; ++k) { fv[k] = DBL_MAX; fl[k] = 0x7fffffff; }
#pragma unroll
        for (int ww = 0; ww < 4; ++ww) {
#pragma unroll
            for (int k = 0; k < TOPK; ++k) {
                double cv = mV[(ww * RT + r) * TOPK + k];
                int    cl = mI[(ww * RT + r) * TOPK + k];
#pragma unroll
                for (int s = 0; s < TOPK; ++s) {
                    bool better = (cv < fv[s]) || (cv == fv[s] && cl < fl[s]);
                    double ov = fv[s]; int ol = fl[s];
                    if (better) { fv[s] = cv; fl[s] = cl; cv = ov; cl = ol; }
                }
            }
        }
        int src = ordR[r];
        float* outRow = out + ((size_t)b * NPTS + src) * NPTS;
#pragma unroll
        for (int k = 0; k < TOPK; ++k) {
            double dist = sqrt(fv[k]);     // fv already clamped
            double dm   = exp(-0.1 * dist);
            int dst = ordBase[fl[k]];      // chunk-local -> global
            outRow[dst] = (float)dm;
        }
    }
}

// ---------------- launch ----------------
extern "C" void kernel_launch(void* const* d_in, const int* in_sizes, int n_in,
                              void* d_out, int out_size, void* d_ws, size_t ws_size,
                              hipStream_t stream) {
    const float* pts = (const float*)d_in[0];   // [2,5000,128]
    const float* rot = (const float*)d_in[1];   // [128,100]
    float* out = (float*)d_out;                 // [2,5000,5000]

    double* na      = (double*)d_ws;                                    // 80000 B
    int*    bin_idx = (int*)((char*)d_ws + 80000);                      // 40000 B
    int*    order   = (int*)((char*)d_ws + 120000);                     // 40000 B

    k_bins<<<(BATCH * NPTS + KB_PTS - 1) / KB_PTS, 256, 0, stream>>>(pts, rot, bin_idx, na);
    k_sort<<<BATCH, 256, 0, stream>>>(bin_idx, order);
    k_chunks<<<BATCH * NBINS * NRT, 256, 0, stream>>>(pts, na, order, out);
}

// Round 3
// 296.989 us; speedup vs baseline: 1.1475x; 1.1475x over previous
//
#include <hip/hip_runtime.h>
#include <cfloat>
#include <math.h>

#define NPTS   5000
#define BATCH  2
#define DIM    128
#define NBINS  10
#define BINSZ  500
#define TOPK   5
#define ROTCOLS 100   // rotations stored [128, 100]; we use first NBINS/2 = 5

// ---------------- Kernel A: bin assignment + squared norms (fp64 acc) -----
#define KB_PTS 64
#define KB_STR 129
__global__ void k_bins(const float* __restrict__ pts, const float* __restrict__ rot,
                       int* __restrict__ bin_idx, double* __restrict__ na) {
    __shared__ float P[KB_PTS * KB_STR];
    __shared__ float rotL[DIM * 5];
    int tid = threadIdx.x;
    for (int f = tid; f < DIM * 5; f += 256)
        rotL[f] = rot[(f / 5) * ROTCOLS + (f % 5)];

    int p0  = blockIdx.x * KB_PTS;
    int npb = min(KB_PTS, BATCH * NPTS - p0);

    for (int f = tid; f < npb * DIM; f += 256) {
        int r = f >> 7, d = f & 127;
        P[r * KB_STR + d] = pts[(size_t)(p0 + r) * DIM + d];
    }
    __syncthreads();

    int p = tid >> 2;    // point within block
    int s = tid & 3;     // dim quarter
    double acc[5] = {0., 0., 0., 0., 0.};
    double sq = 0.;
    const float* row = &P[p * KB_STR + s * 32];
    for (int j = 0; j < 32; ++j) {
        double v = (double)row[j];
        sq += v * v;
        int d = s * 32 + j;
#pragma unroll
        for (int h = 0; h < 5; ++h) acc[h] += v * (double)rotL[d * 5 + h];
    }
#pragma unroll
    for (int m = 1; m < 4; m <<= 1) {
#pragma unroll
        for (int h = 0; h < 5; ++h) acc[h] += __shfl_xor(acc[h], m, 4);
        sq += __shfl_xor(sq, m, 4);
    }
    if (s == 0 && p < npb) {
        double best = acc[0]; int bc = 0;
#pragma unroll
        for (int c = 1; c < NBINS; ++c) {
            double v = (c < 5) ? acc[c] : -acc[c - 5];
            if (v > best) { best = v; bc = c; }
        }
        bin_idx[p0 + p] = bc;
        na[p0 + p] = sq;
    }
}

// ---------------- Kernel B: stable counting sort (== stable argsort) ------
__global__ void k_sort(const int* __restrict__ bin_idx, int* __restrict__ order) {
    const int b = blockIdx.x;
    const int t = threadIdx.x;               // 256 threads
    const int NPT = (NPTS + 255) / 256;      // 20
    int start = t * NPT;
    int end   = min(NPTS, start + NPT);

    int cnt[NBINS];
#pragma unroll
    for (int c = 0; c < NBINS; ++c) cnt[c] = 0;
    for (int i = start; i < end; ++i) {
        int c = bin_idx[b * NPTS + i];
#pragma unroll
        for (int k = 0; k < NBINS; ++k) cnt[k] += (c == k);
    }

    __shared__ int hist[NBINS * 256];
#pragma unroll
    for (int c = 0; c < NBINS; ++c) hist[c * 256 + t] = cnt[c];
    __syncthreads();

    int base = t * NBINS;
    int s = 0;
#pragma unroll
    for (int k = 0; k < NBINS; ++k) s += hist[base + k];
    __shared__ int scan[256];
    scan[t] = s;
    __syncthreads();
    for (int off = 1; off < 256; off <<= 1) {
        int v = (t >= off) ? scan[t - off] : 0;
        __syncthreads();
        scan[t] += v;
        __syncthreads();
    }
    int run = scan[t] - s;
#pragma unroll
    for (int k = 0; k < NBINS; ++k) { int h = hist[base + k]; hist[base + k] = run; run += h; }
    __syncthreads();

    int ofs[NBINS];
#pragma unroll
    for (int c = 0; c < NBINS; ++c) ofs[c] = hist[c * 256 + t];
    for (int i = start; i < end; ++i) {
        int c = bin_idx[b * NPTS + i];
        int pos = 0;
#pragma unroll
        for (int k = 0; k < NBINS; ++k) {
            if (c == k) pos = ofs[k];
            ofs[k] += (c == k);
        }
        order[b * NPTS + pos] = i;
    }
}

// -- Kernel C: layout-deriving f64 MFMA gram + top-5 + zero-fill/scatter ---
// R1 probe evidence: f64 16x16x4 MFMA rejected BOTH {A/B conv1 or conv2 with
// D row=4*(lane>>4)+reg, col=lane&15}. MfmaUtil 0.079% == exactly the probe
// MFMAs -> fallback ran. Consistent with D TRANSPOSED for f64 (row=lane&15,
// col=4*(lane>>4)+reg). This version DERIVES the layout numerically:
//   pB = mfma(1, lane): value 4j+96 (B conv1) or 16j+6 (conv2) -> col per reg
//   pA = mfma(lane, 1): value 4i+96 (A conv1) or 16i+6 (conv2) -> row per reg
//   (families disjoint mod 4), pAB = mfma(lane,lane) cross-checks products.
// Requires row-per-lane (rowConst) + 4 distinct cols; selection uses
// order-independent lexicographic (key,idx) top-5 so runtime col order is
// irrelevant; cross-lane merge goes through LDS keyed by decoded row (no
// shuffle-topology assumption). Any check fails -> verbatim R0 2x2 scalar
// path (124us verified). All selection state static-indexed (scratch trap).
#define RT    16
#define NRT   32
#define CTILE 64
#define RSTRD 130      // rowPd stride in doubles (1040 B rows, 16B-aligned)
#define CSTR  132      // colP stride in floats
#define NCT   8
#define ROWQ  (NPTS/4)

typedef double v4d __attribute__((ext_vector_type(4)));

__launch_bounds__(256, 3)
__global__ void k_chunks(const float* __restrict__ pts, const double* __restrict__ na,
                         const int* __restrict__ order, float* __restrict__ out) {
    __shared__ double rowPd[RT * RSTRD];    // 16640 B (reused as merge buffer at end)
    __shared__ float  colP[CTILE * CSTR];   // 33792 B
    __shared__ double naC[CTILE];
    __shared__ double naRs[RT];
    __shared__ int    ordR[RT];             // ~51.1 KB -> 3 blocks/CU

    int blk   = blockIdx.x;
    int rt    = blk & (NRT - 1);
    int chunk = blk >> 5;          // 0..19
    int b     = chunk / NBINS;
    int c     = chunk % NBINS;
    int tid   = threadIdx.x;
    int row0  = rt * RT;
    int rowCount = min(RT, BINSZ - row0);   // 16, except last tile: 4

    const int*   ordBase = order + b * NPTS + c * BINSZ;
    const float* ptsB    = pts + (size_t)b * NPTS * DIM;

    int lane = tid & 63;
    int w    = tid >> 6;     // wave id 0..3 -> col slab [16w, 16w+16) per tile
    int mm   = lane & 15;
    int gg   = lane >> 4;

    // ---- probe & derive the f64 MFMA fragment layout (register-only) ----
    v4d z4 = {0., 0., 0., 0.};
    v4d pB  = __builtin_amdgcn_mfma_f64_16x16x4f64(1.0, (double)lane, z4, 0, 0, 0);
    v4d pA  = __builtin_amdgcn_mfma_f64_16x16x4f64((double)lane, 1.0, z4, 0, 0, 0);
    v4d pAB = __builtin_amdgcn_mfma_f64_16x16x4f64((double)lane, (double)lane, z4, 0, 0, 0);

    bool ok = true;
    int aconv = 0, bconv = 0;  // 1: idx=lane&15,k=lane>>4 ; 2: idx=lane>>2,k=lane&3
    int rw[4], cj[4];
#pragma unroll
    for (int r = 0; r < 4; ++r) {
        int av = (int)pA[r];
        ok = ok && ((double)av == pA[r]);
        int arow = 0, acv = -1;
        if (av >= 96 && av <= 156 && (av & 3) == 0)       { arow = (av - 96) >> 2; acv = 1; }
        else if (av >= 6 && av <= 246 && (av & 15) == 6)  { arow = (av - 6) >> 4;  acv = 2; }
        else ok = false;
        if (aconv == 0) aconv = acv; else ok = ok && (acv == aconv);
        rw[r] = arow;

        int bv = (int)pB[r];
        ok = ok && ((double)bv == pB[r]);
        int bcol = 0, bcv = -1;
        if (bv >= 96 && bv <= 156 && (bv & 3) == 0)       { bcol = (bv - 96) >> 2; bcv = 1; }
        else if (bv >= 6 && bv <= 246 && (bv & 15) == 6)  { bcol = (bv - 6) >> 4;  bcv = 2; }
        else ok = false;
        if (bconv == 0) bconv = bcv; else ok = ok && (bcv == bconv);
        cj[r] = bcol;
    }
    // product cross-check: pAB[r] must equal sum_k A(row,k)*B(k,col)
#pragma unroll
    for (int r = 0; r < 4; ++r) {
        double e = 0.;
#pragma unroll
        for (int k = 0; k < 4; ++k) {
            double Aval = (aconv == 2) ? (double)(4 * rw[r] + k) : (double)(16 * k + rw[r]);
            double Bval = (bconv == 2) ? (double)(4 * cj[r] + k) : (double)(16 * k + cj[r]);
            e += Aval * Bval;
        }
        ok = ok && (pAB[r] == e);
    }
    ok = ok && (rw[0] == rw[1] && rw[1] == rw[2] && rw[2] == rw[3]);   // row-per-lane
    ok = ok && (cj[0] != cj[1] && cj[0] != cj[2] && cj[0] != cj[3] &&
                cj[1] != cj[2] && cj[1] != cj[3] && cj[2] != cj[3]);   // distinct cols
    bool useMfma = __all(ok) != 0;       // uniform across all waves/blocks
    int rowL = rw[0];

    // stage row points as doubles (gathered via order; cvt once per element)
    for (int f = tid; f < rowCount * (DIM / 4); f += 256) {
        int r = f >> 5;
        int q = f & 31;
        int g = ordBase[row0 + r];
        float4 v = *(const float4*)(ptsB + (size_t)g * DIM + q * 4);
        double2 d01; d01.x = (double)v.x; d01.y = (double)v.y;
        double2 d23; d23.x = (double)v.z; d23.y = (double)v.w;
        *(double2*)(&rowPd[r * RSTRD + q * 4 + 0]) = d01;
        *(double2*)(&rowPd[r * RSTRD + q * 4 + 2]) = d23;
    }
    if (tid < rowCount) {
        int g = ordBase[row0 + tid];
        ordR[tid] = g;
        naRs[tid] = na[b * NPTS + g];
    }
    __syncthreads();

    const int totalZ = rowCount * ROWQ;

    if (useMfma) {
        // ================= MFMA path (derived layout) =================
        int iA = (aconv == 2) ? (lane >> 2) : mm;
        int kA = (aconv == 2) ? (lane & 3)  : gg;
        int jB = (bconv == 2) ? (lane >> 2) : mm;
        int kB = (bconv == 2) ? (lane & 3)  : gg;
        const double* aBase = &rowPd[iA * RSTRD + kA];          // A[iA][4s+kA]
        const float*  bBase = &colP[(16 * w + jB) * CSTR + kB]; // B col 16w+jB, dim 4s+kB

        double naRow = naRs[rowL];   // garbage for rowL>=rowCount; discarded at merge

        double tv[TOPK]; int tl[TOPK];
#pragma unroll
        for (int k = 0; k < TOPK; ++k) { tv[k] = DBL_MAX; tl[k] = 0x7fffffff; }

        for (int ct = 0; ct < NCT; ++ct) {
            int col0 = ct * CTILE;
            int colCount = min(CTILE, BINSZ - col0);
            __syncthreads();   // prev tile's readers done before restage
            for (int f = tid; f < colCount * (DIM / 4); f += 256) {
                int j = f >> 5;
                int q = f & 31;
                int g = ordBase[col0 + j];
                float4 v = *(const float4*)(ptsB + (size_t)g * DIM + q * 4);
                *(float4*)(&colP[j * CSTR + q * 4]) = v;
            }
            if (tid < colCount) {
                int g = ordBase[col0 + tid];
                naC[tid] = na[b * NPTS + g];
            }
            __syncthreads();

            // zero-fill slice ct: stores drain during this tile's gram compute
            {
                float4 z = make_float4(0.f, 0.f, 0.f, 0.f);
                int z0 = (ct * totalZ) / NCT, z1 = ((ct + 1) * totalZ) / NCT;
                for (int f = z0 + tid; f < z1; f += 256) {
                    int r = f / ROWQ;
                    int q = f - r * ROWQ;
                    float* outRow = out + ((size_t)b * NPTS + ordR[r]) * NPTS;
                    *(float4*)(outRow + 4 * q) = z;
                }
            }

            // gram: wave computes rows 0..15 x cols [16w,16w+16) via f64 MFMA
            v4d acc = {0., 0., 0., 0.};
#pragma unroll
            for (int s = 0; s < 32; ++s) {
                double av = aBase[4 * s];
                double bv = (double)bBase[4 * s];
                acc = __builtin_amdgcn_mfma_f64_16x16x4f64(av, bv, acc, 0, 0, 0);
            }

            // lane holds row rowL x 4 cols (decoded); lexicographic top-5
            // (order-independent), so runtime col order is fine.
#pragma unroll
            for (int r = 0; r < 4; ++r) {
                int j16 = 16 * w + cj[r];
                if (j16 < colCount) {
                    int    ci = col0 + j16;
                    double cv = fmax(naRow + naC[j16] - 2. * acc[r], 1e-6);
#pragma unroll
                    for (int k = 0; k < TOPK; ++k) {
                        bool better = (cv < tv[k]) || (cv == tv[k] && ci < tl[k]);
                        double ov = tv[k]; int ol = tl[k];
                        if (better) { tv[k] = cv; tl[k] = ci; cv = ov; ci = ol; }
                    }
                }
            }
        }

        // generic merge through LDS keyed by decoded row (no shuffle topology
        // assumption). Reuse rowPd: 256*5 dbl + 256*5 int + 256 int = 2048 dbl
        // worth <= 2080. All gram reads done before overwrite.
        __syncthreads();   // gram reads + last zero slice drained
        double* mV = rowPd;                               // [tid*5+k]
        int*    mI = reinterpret_cast<int*>(rowPd + 1280);
        int*    mR = reinterpret_cast<int*>(rowPd + 1920);
#pragma unroll
        for (int k = 0; k < TOPK; ++k) { mV[tid * TOPK + k] = tv[k]; mI[tid * TOPK + k] = tl[k]; }
        mR[tid] = rowL;
        __syncthreads();

        if (tid < RT && tid < rowCount) {
            double fv[TOPK]; int fl[TOPK];
#pragma unroll
            for (int k = 0; k < TOPK; ++k) { fv[k] = DBL_MAX; fl[k] = 0x7fffffff; }
            for (int src = 0; src < 256; ++src) {
                if (mR[src] == tid) {
#pragma unroll
                    for (int k = 0; k < TOPK; ++k) {
                        double cv = mV[src * TOPK + k];
                        int    cl = mI[src * TOPK + k];
#pragma unroll
                        for (int s = 0; s < TOPK; ++s) {
                            bool better = (cv < fv[s]) || (cv == fv[s] && cl < fl[s]);
                            double ov = fv[s]; int ol = fl[s];
                            if (better) { fv[s] = cv; fl[s] = cl; cv = ov; cl = ol; }
                        }
                    }
                }
            }
            int src = ordR[tid];
            float* outRow = out + ((size_t)b * NPTS + src) * NPTS;
#pragma unroll
            for (int k = 0; k < TOPK; ++k) {
                double dist = sqrt(fv[k]);     // fv already clamped
                double dm   = exp(-0.1 * dist);
                int dst = ordBase[fl[k]];      // chunk-local -> global
                outRow[dst] = (float)dm;
            }
        }
    } else {
        // ============ fallback: verbatim R0 2x2 scalar path (124us) ============
        int rg = tid >> 5;   // 0..7 : rows rg, rg+8
        int cg = tid & 31;   // 0..31: cols cg, cg+32

        double naRr0 = (rg     < rowCount) ? naRs[rg]     : 0.;
        double naRr1 = (rg + 8 < rowCount) ? naRs[rg + 8] : 0.;

        double tv[2][TOPK];
        int    tl[2][TOPK];
#pragma unroll
        for (int ii = 0; ii < 2; ++ii)
#pragma unroll
            for (int k = 0; k < TOPK; ++k) { tv[ii][k] = DBL_MAX; tl[ii][k] = 0x7fffffff; }

        for (int ct = 0; ct < NCT; ++ct) {
            int col0 = ct * CTILE;
            int colCount = min(CTILE, BINSZ - col0);
            __syncthreads();
            for (int f = tid; f < colCount * (DIM / 4); f += 256) {
                int j = f >> 5;
                int q = f & 31;
                int g = ordBase[col0 + j];
                float4 v = *(const float4*)(ptsB + (size_t)g * DIM + q * 4);
                *(float4*)(&colP[j * CSTR + q * 4]) = v;
            }
            if (tid < colCount) {
                int g = ordBase[col0 + tid];
                naC[tid] = na[b * NPTS + g];
            }
            __syncthreads();

            {
                float4 z = make_float4(0.f, 0.f, 0.f, 0.f);
                int z0 = (ct * totalZ) / NCT, z1 = ((ct + 1) * totalZ) / NCT;
                for (int f = z0 + tid; f < z1; f += 256) {
                    int r = f / ROWQ;
                    int q = f - r * ROWQ;
                    float* outRow = out + ((size_t)b * NPTS + ordR[r]) * NPTS;
                    *(float4*)(outRow + 4 * q) = z;
                }
            }

            double acc00 = 0., acc01 = 0., acc10 = 0., acc11 = 0.;

            for (int q = 0; q < DIM / 4; ++q) {
                double2 a0lo = *(const double2*)(&rowPd[rg * RSTRD + q * 4 + 0]);
                double2 a0hi = *(const double2*)(&rowPd[rg * RSTRD + q * 4 + 2]);
                double2 a1lo = *(const double2*)(&rowPd[(rg + 8) * RSTRD + q * 4 + 0]);
                double2 a1hi = *(const double2*)(&rowPd[(rg + 8) * RSTRD + q * 4 + 2]);
                float4 b0 = *(const float4*)(&colP[cg * CSTR + q * 4]);
                float4 b1 = *(const float4*)(&colP[(cg + 32) * CSTR + q * 4]);
                double b00 = (double)b0.x, b01 = (double)b0.y,
                       b02 = (double)b0.z, b03 = (double)b0.w;
                double b10 = (double)b1.x, b11 = (double)b1.y,
                       b12 = (double)b1.z, b13 = (double)b1.w;
                acc00 += a0lo.x * b00 + a0lo.y * b01 + a0hi.x * b02 + a0hi.y * b03;
                acc01 += a0lo.x * b10 + a0lo.y * b11 + a0hi.x * b12 + a0hi.y * b13;
                acc10 += a1lo.x * b00 + a1lo.y * b01 + a1hi.x * b02 + a1hi.y * b03;
                acc11 += a1lo.x * b10 + a1lo.y * b11 + a1hi.x * b12 + a1hi.y * b13;
            }

#pragma unroll
            for (int jj = 0; jj < 2; ++jj) {
                int j = cg + 32 * jj;
                if (j < colCount) {
                    int    cl = col0 + j;
                    double nc = naC[j];
                    double a0 = (jj == 0) ? acc00 : acc01;
                    double a1 = (jj == 0) ? acc10 : acc11;
                    double cv0 = fmax(naRr0 + nc - 2. * a0, 1e-6);
                    double cv1 = fmax(naRr1 + nc - 2. * a1, 1e-6);
                    int cl0 = cl, cl1 = cl;
#pragma unroll
                    for (int k = 0; k < TOPK; ++k) {
                        bool lt0 = (cv0 < tv[0][k]);
                        double ov0 = tv[0][k]; int ol0 = tl[0][k];
                        if (lt0) { tv[0][k] = cv0; tl[0][k] = cl0; cv0 = ov0; cl0 = ol0; }
                        bool lt1 = (cv1 < tv[1][k]);
                        double ov1 = tv[1][k]; int ol1 = tl[1][k];
                        if (lt1) { tv[1][k] = cv1; tl[1][k] = cl1; cv1 = ov1; cl1 = ol1; }
                    }
                }
            }
        }

#pragma unroll
        for (int m = 1; m < 32; m <<= 1) {
#pragma unroll
            for (int ii = 0; ii < 2; ++ii) {
                double rv[TOPK]; int rl[TOPK];
#pragma unroll
                for (int k = 0; k < TOPK; ++k) {
                    rv[k] = __shfl_xor(tv[ii][k], m, 32);
                    rl[k] = __shfl_xor(tl[ii][k], m, 32);
                }
#pragma unroll
                for (int k = 0; k < TOPK; ++k) {
                    double cv = rv[k]; int cl = rl[k];
#pragma unroll
                    for (int s = 0; s < TOPK; ++s) {
                        bool better = (cv < tv[ii][s]) || (cv == tv[ii][s] && cl < tl[ii][s]);
                        double ov = tv[ii][s]; int ol = tl[ii][s];
                        if (better) { tv[ii][s] = cv; tl[ii][s] = cl; cv = ov; cl = ol; }
                    }
                }
            }
        }

        __syncthreads();   // drain last zero slice before value scatter

        if (cg == 0) {
#pragma unroll
            for (int ii = 0; ii < 2; ++ii) {
                int r = rg + 8 * ii;
                if (r < rowCount) {
                    int src = ordR[r];
                    float* outRow = out + ((size_t)b * NPTS + src) * NPTS;
#pragma unroll
                    for (int k = 0; k < TOPK; ++k) {
                        double dist = sqrt(tv[ii][k]);
                        double dm   = exp(-0.1 * dist);
                        int dst = ordBase[tl[ii][k]];
                        outRow[dst] = (float)dm;
                    }
                }
            }
        }
    }
}

// ---------------- launch ----------------
extern "C" void kernel_launch(void* const* d_in, const int* in_sizes, int n_in,
                              void* d_out, int out_size, void* d_ws, size_t ws_size,
                              hipStream_t stream) {
    const float* pts = (const float*)d_in[0];   // [2,5000,128]
    const float* rot = (const float*)d_in[1];   // [128,100]
    float* out = (float*)d_out;                 // [2,5000,5000]

    double* na      = (double*)d_ws;                                    // 80000 B
    int*    bin_idx = (int*)((char*)d_ws + 80000);                      // 40000 B
    int*    order   = (int*)((char*)d_ws + 120000);                     // 40000 B

    k_bins<<<(BATCH * NPTS + KB_PTS - 1) / KB_PTS, 256, 0, stream>>>(pts, rot, bin_idx, na);
    k_sort<<<BATCH, 256, 0, stream>>>(bin_idx, order);
    k_chunks<<<BATCH * NBINS * NRT, 256, 0, stream>>>(pts, na, order, out);
}

// Round 4
// 294.475 us; speedup vs baseline: 1.1573x; 1.0085x over previous
//
#include <hip/hip_runtime.h>
#include <cfloat>
#include <math.h>

#define NPTS   5000
#define BATCH  2
#define DIM    128
#define NBINS  10
#define BINSZ  500
#define TOPK   5
#define ROTCOLS 100   // rotations stored [128, 100]; we use first NBINS/2 = 5

// ---------------- Kernel A: bin assignment + squared norms (fp64 acc) -----
#define KB_PTS 64
#define KB_STR 129
__global__ void k_bins(const float* __restrict__ pts, const float* __restrict__ rot,
                       int* __restrict__ bin_idx, double* __restrict__ na) {
    __shared__ float P[KB_PTS * KB_STR];
    __shared__ float rotL[DIM * 5];
    int tid = threadIdx.x;
    for (int f = tid; f < DIM * 5; f += 256)
        rotL[f] = rot[(f / 5) * ROTCOLS + (f % 5)];

    int p0  = blockIdx.x * KB_PTS;
    int npb = min(KB_PTS, BATCH * NPTS - p0);

    for (int f = tid; f < npb * DIM; f += 256) {
        int r = f >> 7, d = f & 127;
        P[r * KB_STR + d] = pts[(size_t)(p0 + r) * DIM + d];
    }
    __syncthreads();

    int p = tid >> 2;    // point within block
    int s = tid & 3;     // dim quarter
    double acc[5] = {0., 0., 0., 0., 0.};
    double sq = 0.;
    const float* row = &P[p * KB_STR + s * 32];
    for (int j = 0; j < 32; ++j) {
        double v = (double)row[j];
        sq += v * v;
        int d = s * 32 + j;
#pragma unroll
        for (int h = 0; h < 5; ++h) acc[h] += v * (double)rotL[d * 5 + h];
    }
#pragma unroll
    for (int m = 1; m < 4; m <<= 1) {
#pragma unroll
        for (int h = 0; h < 5; ++h) acc[h] += __shfl_xor(acc[h], m, 4);
        sq += __shfl_xor(sq, m, 4);
    }
    if (s == 0 && p < npb) {
        double best = acc[0]; int bc = 0;
#pragma unroll
        for (int c = 1; c < NBINS; ++c) {
            double v = (c < 5) ? acc[c] : -acc[c - 5];
            if (v > best) { best = v; bc = c; }
        }
        bin_idx[p0 + p] = bc;
        na[p0 + p] = sq;
    }
}

// ---------------- Kernel B: stable counting sort (== stable argsort) ------
__global__ void k_sort(const int* __restrict__ bin_idx, int* __restrict__ order) {
    const int b = blockIdx.x;
    const int t = threadIdx.x;               // 256 threads
    const int NPT = (NPTS + 255) / 256;      // 20
    int start = t * NPT;
    int end   = min(NPTS, start + NPT);

    int cnt[NBINS];
#pragma unroll
    for (int c = 0; c < NBINS; ++c) cnt[c] = 0;
    for (int i = start; i < end; ++i) {
        int c = bin_idx[b * NPTS + i];
#pragma unroll
        for (int k = 0; k < NBINS; ++k) cnt[k] += (c == k);
    }

    __shared__ int hist[NBINS * 256];
#pragma unroll
    for (int c = 0; c < NBINS; ++c) hist[c * 256 + t] = cnt[c];
    __syncthreads();

    int base = t * NBINS;
    int s = 0;
#pragma unroll
    for (int k = 0; k < NBINS; ++k) s += hist[base + k];
    __shared__ int scan[256];
    scan[t] = s;
    __syncthreads();
    for (int off = 1; off < 256; off <<= 1) {
        int v = (t >= off) ? scan[t - off] : 0;
        __syncthreads();
        scan[t] += v;
        __syncthreads();
    }
    int run = scan[t] - s;
#pragma unroll
    for (int k = 0; k < NBINS; ++k) { int h = hist[base + k]; hist[base + k] = run; run += h; }
    __syncthreads();

    int ofs[NBINS];
#pragma unroll
    for (int c = 0; c < NBINS; ++c) ofs[c] = hist[c * 256 + t];
    for (int i = start; i < end; ++i) {
        int c = bin_idx[b * NPTS + i];
        int pos = 0;
#pragma unroll
        for (int k = 0; k < NBINS; ++k) {
            if (c == k) pos = ofs[k];
            ofs[k] += (c == k);
        }
        order[b * NPTS + pos] = i;
    }
}

// -- Kernel C: k-split 2x4 f64 gram + top-5 + zero-fill/scatter ------------
// History: f64 MFMA (v_mfma_f64_16x16x4f64) abandoned after R0-R2: probe
// values match NO layout family; consistent with the instruction returning
// zeros on gfx950 (CDNA4 cut f64 matrix HW; ISA-doc entry is a CDNA3
// carry-over). Do not revisit without external evidence it works.
// This version: k-split register tiling. Threads = (cg 0..15, ks 0..1,
// rg 0..7); each thread computes rows {rg, rg+8} x cols {cg,+16,+32,+48}
// over dims [64ks, 64ks+64), then one shfl_xor(16) per acc merges k-halves.
// vs R0 2x2: per-thread LDS reads 1536 -> 1024 (-33%), B-read bank
// conflicts 4-way -> 2-way, 8 independent half-length acc chains (2x ILP).
// FMA/cvt totals unchanged. Selection ownership: ks=0 -> cols {cg,cg+16},
// ks=1 -> {cg+32,cg+48}; each (row,col) owned by exactly one thread,
// ascending arrival -> strict-< insertion == (key asc, idx asc). Merge:
// width-32 butterfly (half-waves share the row pair) -- verbatim R0 logic.
// NOTE: register prefetch / 8-wide candidate state / one-barrier variants
// regressed via scratch traffic; all selection state static-indexed.
#define RT    16
#define NRT   32
#define CTILE 64
#define RSTRD 130      // rowPd stride in doubles (1040 B rows, 16B-aligned)
#define CSTR  132      // colP stride in floats
#define NCT   8
#define ROWQ  (NPTS/4)

__launch_bounds__(256, 3)
__global__ void k_chunks(const float* __restrict__ pts, const double* __restrict__ na,
                         const int* __restrict__ order, float* __restrict__ out) {
    __shared__ double rowPd[RT * RSTRD];    // 16640 B
    __shared__ float  colP[CTILE * CSTR];   // 33792 B
    __shared__ double naC[CTILE];
    __shared__ double naRs[RT];
    __shared__ int    ordR[RT];             // ~51.1 KB -> 3 blocks/CU

    int blk   = blockIdx.x;
    int rt    = blk & (NRT - 1);
    int chunk = blk >> 5;          // 0..19
    int b     = chunk / NBINS;
    int c     = chunk % NBINS;
    int tid   = threadIdx.x;
    int row0  = rt * RT;
    int rowCount = min(RT, BINSZ - row0);   // 16, except last tile: 4

    const int*   ordBase = order + b * NPTS + c * BINSZ;
    const float* ptsB    = pts + (size_t)b * NPTS * DIM;

    // stage row points as doubles (gathered via order; cvt once per element)
    for (int f = tid; f < rowCount * (DIM / 4); f += 256) {
        int r = f >> 5;
        int q = f & 31;
        int g = ordBase[row0 + r];
        float4 v = *(const float4*)(ptsB + (size_t)g * DIM + q * 4);
        double2 d01; d01.x = (double)v.x; d01.y = (double)v.y;
        double2 d23; d23.x = (double)v.z; d23.y = (double)v.w;
        *(double2*)(&rowPd[r * RSTRD + q * 4 + 0]) = d01;
        *(double2*)(&rowPd[r * RSTRD + q * 4 + 2]) = d23;
    }
    if (tid < rowCount) {
        int g = ordBase[row0 + tid];
        ordR[tid] = g;
        naRs[tid] = na[b * NPTS + g];
    }
    __syncthreads();

    int cg  = tid & 15;         // col group: cols cg, cg+16, cg+32, cg+48
    int ks  = (tid >> 4) & 1;   // k-half: dims [64ks, 64ks+64)
    int rg  = tid >> 5;         // 0..7: rows rg, rg+8
    int cgm = tid & 31;         // merge-lane id within half-wave (verbatim R0 role)
    const int q0 = ks * 64;

    double naRr0 = (rg     < rowCount) ? naRs[rg]     : 0.;
    double naRr1 = (rg + 8 < rowCount) ? naRs[rg + 8] : 0.;

    // selection key: clamped squared distance (smaller = better); bottom-5,
    // strict < with in-order arrival == (key asc, idx asc), matches ref.
    double tv[2][TOPK];
    int    tl[2][TOPK];
#pragma unroll
    for (int ii = 0; ii < 2; ++ii)
#pragma unroll
        for (int k = 0; k < TOPK; ++k) { tv[ii][k] = DBL_MAX; tl[ii][k] = 0x7fffffff; }

    const int totalZ = rowCount * ROWQ;

    for (int ct = 0; ct < NCT; ++ct) {
        int col0T = ct * CTILE;
        int colCount = min(CTILE, BINSZ - col0T);
        __syncthreads();   // prev tile's readers done before restage
        for (int f = tid; f < colCount * (DIM / 4); f += 256) {
            int j = f >> 5;
            int q = f & 31;
            int g = ordBase[col0T + j];
            float4 v = *(const float4*)(ptsB + (size_t)g * DIM + q * 4);
            *(float4*)(&colP[j * CSTR + q * 4]) = v;
        }
        if (tid < colCount) {
            int g = ordBase[col0T + tid];
            naC[tid] = na[b * NPTS + g];
        }
        __syncthreads();

        // zero-fill slice ct: stores drain during this tile's gram compute
        {
            float4 z = make_float4(0.f, 0.f, 0.f, 0.f);
            int z0 = (ct * totalZ) / NCT, z1 = ((ct + 1) * totalZ) / NCT;
            for (int f = z0 + tid; f < z1; f += 256) {
                int r = f / ROWQ;
                int q = f - r * ROWQ;
                float* outRow = out + ((size_t)b * NPTS + ordR[r]) * NPTS;
                *(float4*)(outRow + 4 * q) = z;
            }
        }

        // gram: rows {rg, rg+8} x cols {cg,+16,+32,+48}, dims [q0, q0+64)
        double acc00 = 0., acc01 = 0., acc02 = 0., acc03 = 0.;
        double acc10 = 0., acc11 = 0., acc12 = 0., acc13 = 0.;

        for (int q = 0; q < 64; q += 4) {
            const int qq = q0 + q;
            double2 a0lo = *(const double2*)(&rowPd[rg * RSTRD + qq + 0]);
            double2 a0hi = *(const double2*)(&rowPd[rg * RSTRD + qq + 2]);
            double2 a1lo = *(const double2*)(&rowPd[(rg + 8) * RSTRD + qq + 0]);
            double2 a1hi = *(const double2*)(&rowPd[(rg + 8) * RSTRD + qq + 2]);
            float4 f0 = *(const float4*)(&colP[cg * CSTR + qq]);
            float4 f1 = *(const float4*)(&colP[(cg + 16) * CSTR + qq]);
            float4 f2 = *(const float4*)(&colP[(cg + 32) * CSTR + qq]);
            float4 f3 = *(const float4*)(&colP[(cg + 48) * CSTR + qq]);
            double b0x = (double)f0.x, b0y = (double)f0.y, b0z = (double)f0.z, b0w = (double)f0.w;
            double b1x = (double)f1.x, b1y = (double)f1.y, b1z = (double)f1.z, b1w = (double)f1.w;
            double b2x = (double)f2.x, b2y = (double)f2.y, b2z = (double)f2.z, b2w = (double)f2.w;
            double b3x = (double)f3.x, b3y = (double)f3.y, b3z = (double)f3.z, b3w = (double)f3.w;
            acc00 += a0lo.x * b0x + a0lo.y * b0y + a0hi.x * b0z + a0hi.y * b0w;
            acc01 += a0lo.x * b1x + a0lo.y * b1y + a0hi.x * b1z + a0hi.y * b1w;
            acc02 += a0lo.x * b2x + a0lo.y * b2y + a0hi.x * b2z + a0hi.y * b2w;
            acc03 += a0lo.x * b3x + a0lo.y * b3y + a0hi.x * b3z + a0hi.y * b3w;
            acc10 += a1lo.x * b0x + a1lo.y * b0y + a1hi.x * b0z + a1hi.y * b0w;
            acc11 += a1lo.x * b1x + a1lo.y * b1y + a1hi.x * b1z + a1hi.y * b1w;
            acc12 += a1lo.x * b2x + a1lo.y * b2y + a1hi.x * b2z + a1hi.y * b2w;
            acc13 += a1lo.x * b3x + a1lo.y * b3y + a1hi.x * b3z + a1hi.y * b3w;
        }

        // combine k-halves: partner lane = lane^16 (same cg, same rg)
        acc00 += __shfl_xor(acc00, 16, 64);
        acc01 += __shfl_xor(acc01, 16, 64);
        acc02 += __shfl_xor(acc02, 16, 64);
        acc03 += __shfl_xor(acc03, 16, 64);
        acc10 += __shfl_xor(acc10, 16, 64);
        acc11 += __shfl_xor(acc11, 16, 64);
        acc12 += __shfl_xor(acc12, 16, 64);
        acc13 += __shfl_xor(acc13, 16, 64);

        // selection ownership: ks=0 -> cols {cg, cg+16}; ks=1 -> {cg+32, cg+48}
        double selA0 = ks ? acc02 : acc00;   // row rg,   first owned col
        double selA1 = ks ? acc12 : acc10;   // row rg+8, first owned col
        double selB0 = ks ? acc03 : acc01;   // row rg,   second owned col
        double selB1 = ks ? acc13 : acc11;   // row rg+8, second owned col
        int colA = cg + (ks ? 32 : 0);
        int colB = cg + (ks ? 48 : 16);

        if (colA < colCount) {
            int    cl = col0T + colA;
            double nc = naC[colA];
            double cv0 = fmax(naRr0 + nc - 2. * selA0, 1e-6);
            double cv1 = fmax(naRr1 + nc - 2. * selA1, 1e-6);
            int cl0 = cl, cl1 = cl;
#pragma unroll
            for (int k = 0; k < TOPK; ++k) {   // strict <: equal keeps earlier idx
                bool lt0 = (cv0 < tv[0][k]);
                double ov0 = tv[0][k]; int ol0 = tl[0][k];
                if (lt0) { tv[0][k] = cv0; tl[0][k] = cl0; cv0 = ov0; cl0 = ol0; }
                bool lt1 = (cv1 < tv[1][k]);
                double ov1 = tv[1][k]; int ol1 = tl[1][k];
                if (lt1) { tv[1][k] = cv1; tl[1][k] = cl1; cv1 = ov1; cl1 = ol1; }
            }
        }
        if (colB < colCount) {
            int    cl = col0T + colB;
            double nc = naC[colB];
            double cv0 = fmax(naRr0 + nc - 2. * selB0, 1e-6);
            double cv1 = fmax(naRr1 + nc - 2. * selB1, 1e-6);
            int cl0 = cl, cl1 = cl;
#pragma unroll
            for (int k = 0; k < TOPK; ++k) {
                bool lt0 = (cv0 < tv[0][k]);
                double ov0 = tv[0][k]; int ol0 = tl[0][k];
                if (lt0) { tv[0][k] = cv0; tl[0][k] = cl0; cv0 = ov0; cl0 = ol0; }
                bool lt1 = (cv1 < tv[1][k]);
                double ov1 = tv[1][k]; int ol1 = tl[1][k];
                if (lt1) { tv[1][k] = cv1; tl[1][k] = cl1; cv1 = ov1; cl1 = ol1; }
            }
        }
    }

    // merge across the 32 threads of each half-wave (all share rows rg, rg+8;
    // they own disjoint col sets covering 0..499) -- verbatim R0 butterfly.
#pragma unroll
    for (int m = 1; m < 32; m <<= 1) {
#pragma unroll
        for (int ii = 0; ii < 2; ++ii) {
            double rv[TOPK]; int rl[TOPK];
#pragma unroll
            for (int k = 0; k < TOPK; ++k) {
                rv[k] = __shfl_xor(tv[ii][k], m, 32);
                rl[k] = __shfl_xor(tl[ii][k], m, 32);
            }
#pragma unroll
            for (int k = 0; k < TOPK; ++k) {
                double cv = rv[k]; int cl = rl[k];
#pragma unroll
                for (int s = 0; s < TOPK; ++s) {   // (key asc, idx asc) total order
                    bool better = (cv < tv[ii][s]) || (cv == tv[ii][s] && cl < tl[ii][s]);
                    double ov = tv[ii][s]; int ol = tl[ii][s];
                    if (better) { tv[ii][s] = cv; tl[ii][s] = cl; cv = ov; cl = ol; }
                }
            }
        }
    }

    __syncthreads();   // drain last zero slice before value scatter

    // scatter: lane cgm==0 of each half-wave writes 2 rows x 5 values
    if (cgm == 0) {
#pragma unroll
        for (int ii = 0; ii < 2; ++ii) {
            int r = rg + 8 * ii;
            if (r < rowCount) {
                int src = ordR[r];
                float* outRow = out + ((size_t)b * NPTS + src) * NPTS;
#pragma unroll
                for (int k = 0; k < TOPK; ++k) {
                    double dist = sqrt(tv[ii][k]);     // tv already clamped
                    double dm   = exp(-0.1 * dist);
                    int dst = ordBase[tl[ii][k]];      // chunk-local -> global
                    outRow[dst] = (float)dm;
                }
            }
        }
    }
}

// ---------------- launch ----------------
extern "C" void kernel_launch(void* const* d_in, const int* in_sizes, int n_in,
                              void* d_out, int out_size, void* d_ws, size_t ws_size,
                              hipStream_t stream) {
    const float* pts = (const float*)d_in[0];   // [2,5000,128]
    const float* rot = (const float*)d_in[1];   // [128,100]
    float* out = (float*)d_out;                 // [2,5000,5000]

    double* na      = (double*)d_ws;                                    // 80000 B
    int*    bin_idx = (int*)((char*)d_ws + 80000);                      // 40000 B
    int*    order   = (int*)((char*)d_ws + 120000);                     // 40000 B

    k_bins<<<(BATCH * NPTS + KB_PTS - 1) / KB_PTS, 256, 0, stream>>>(pts, rot, bin_idx, na);
    k_sort<<<BATCH, 256, 0, stream>>>(bin_idx, order);
    k_chunks<<<BATCH * NBINS * NRT, 256, 0, stream>>>(pts, na, order, out);
}